// Round 4
// baseline (446.679 us; speedup 1.0000x reference)
//
#include <hip/hip_runtime.h>

typedef __attribute__((ext_vector_type(8))) short short8;
typedef __attribute__((ext_vector_type(4))) float floatx4;
typedef __attribute__((ext_vector_type(4))) int intx4;

#define NPIX 4096
#define CH 256

static __device__ __forceinline__ unsigned short f2bf(float f) {
  union { float f; unsigned int u; } v; v.f = f;
  unsigned int u = v.u;
  return (unsigned short)((u + 0x7FFFu + ((u >> 16) & 1u)) >> 16);
}

static __device__ __forceinline__ unsigned long long pack4bf(floatx4 v) {
  return (unsigned long long)f2bf(v[0]) | ((unsigned long long)f2bf(v[1]) << 16) |
         ((unsigned long long)f2bf(v[2]) << 32) | ((unsigned long long)f2bf(v[3]) << 48);
}

static __device__ __forceinline__ float bf2f(unsigned int u16) {
  union { unsigned int u; float f; } v; v.u = u16 << 16; return v.f;
}

typedef __attribute__((address_space(3))) unsigned int lds_uint;
typedef const __attribute__((address_space(1))) unsigned int glob_uint;
static __device__ __forceinline__ void gload16(const void* g, void* l) {
  __builtin_amdgcn_global_load_lds((glob_uint*)g, (lds_uint*)l, 16, 0, 0);
}

// ---------------- weights fp32 -> bf16 ----------------
__global__ void conv_weights_kernel(const float* __restrict__ wq, const float* __restrict__ wk,
                                    const float* __restrict__ wv, const float* __restrict__ wo,
                                    unsigned short* __restrict__ wqkv, unsigned short* __restrict__ wob) {
  int i = blockIdx.x * 256 + threadIdx.x;   // 0..65535
  wqkv[i]          = f2bf(wq[i]);
  wqkv[65536 + i]  = f2bf(wk[i]);
  wqkv[131072 + i] = f2bf(wv[i]);
  wob[i]           = f2bf(wo[i]);
}

// ---------------- GroupNorm -> xnT bf16 [b][n][c] ----------------
__global__ __launch_bounds__(256) void gn_kernel(const float* __restrict__ x,
                                                 const float* __restrict__ gsc,
                                                 const float* __restrict__ gbi,
                                                 unsigned short* __restrict__ xnT) {
  int blk = blockIdx.x; int b = blk >> 5; int g = blk & 31;
  int c0 = g * 8;
  const float* xb = x + ((size_t)b * CH + c0) * NPIX;
  int tid = threadIdx.x;
  float s = 0.f, ss = 0.f;
#pragma unroll
  for (int ci = 0; ci < 8; ++ci) {
    const floatx4* p = (const floatx4*)(xb + (size_t)ci * NPIX);
    for (int n4 = tid; n4 < 1024; n4 += 256) {
      floatx4 v = p[n4];
      s += v[0] + v[1] + v[2] + v[3];
      ss += v[0]*v[0] + v[1]*v[1] + v[2]*v[2] + v[3]*v[3];
    }
  }
#pragma unroll
  for (int o = 32; o > 0; o >>= 1) { s += __shfl_down(s, o); ss += __shfl_down(ss, o); }
  __shared__ float red[10];
  int wid = tid >> 6;
  if ((tid & 63) == 0) { red[wid] = s; red[4 + wid] = ss; }
  __syncthreads();
  if (tid == 0) {
    float S = red[0] + red[1] + red[2] + red[3];
    float SS = red[4] + red[5] + red[6] + red[7];
    float mean = S * (1.f / 32768.f);
    float var = SS * (1.f / 32768.f) - mean * mean;
    red[8] = mean; red[9] = rsqrtf(var + 1e-5f);
  }
  __syncthreads();
  float mean = red[8], rstd = red[9];
  float sc[8], bi[8];
#pragma unroll
  for (int ci = 0; ci < 8; ++ci) {
    float scale = gsc[c0 + ci] * rstd;
    sc[ci] = scale;
    bi[ci] = gbi[c0 + ci] - mean * scale;
  }
  for (int n4 = tid; n4 < 1024; n4 += 256) {
    floatx4 v[8];
#pragma unroll
    for (int ci = 0; ci < 8; ++ci) v[ci] = ((const floatx4*)(xb + (size_t)ci * NPIX))[n4];
#pragma unroll
    for (int j = 0; j < 4; ++j) {
      alignas(16) unsigned short tmp[8];
#pragma unroll
      for (int ci = 0; ci < 8; ++ci) tmp[ci] = f2bf(v[ci][j] * sc[ci] + bi[ci]);
      *(intx4*)(xnT + ((size_t)(b * NPIX + n4 * 4 + j)) * CH + c0) = *(const intx4*)tmp;
    }
  }
}

// ---------------- QKV GEMM: D[o,n] = sum_c W[o,c]*xnT[n,c] + bias ----------------
// q pre-scaled by log2e/16 (fold of 1/sqrt(256) score scale + exp2 conversion)
// q,k written [n][o] bf16 ; v written [o][n] bf16
__global__ __launch_bounds__(256, 2) void qkv_gemm(
    const unsigned short* __restrict__ wqkv, const unsigned short* __restrict__ xnT,
    const float* __restrict__ bq, const float* __restrict__ bk, const float* __restrict__ bv,
    unsigned short* __restrict__ qT, unsigned short* __restrict__ kT, unsigned short* __restrict__ vC) {
  int nt = blockIdx.x, ot = blockIdx.y, bz = blockIdx.z;
  int which = bz % 3, b = bz / 3;
  const unsigned short* W = wqkv + which * 65536;
  const float* bias = which == 0 ? bq : (which == 1 ? bk : bv);
  const unsigned short* X = xnT + (size_t)b * NPIX * CH;
  int o0 = ot * 128, n0 = nt * 128;

  __shared__ unsigned short As[128 * 64];
  __shared__ unsigned short Bs[128 * 64];

  int tid = threadIdx.x;
  int wave = tid >> 6, lane = tid & 63, quad = lane >> 4, l16 = lane & 15;
  int wm = (wave >> 1) * 64, wn = (wave & 1) * 64;

  floatx4 acc[4][4];
#pragma unroll
  for (int i = 0; i < 4; ++i)
#pragma unroll
    for (int j = 0; j < 4; ++j) acc[i][j] = (floatx4){0.f, 0.f, 0.f, 0.f};

  for (int k0 = 0; k0 < 256; k0 += 64) {
    __syncthreads();
#pragma unroll
    for (int c2 = 0; c2 < 4; ++c2) {
      int row = wave * 32 + c2 * 8 + (lane >> 3);
      int sc = (lane & 7) ^ (row & 7);
      gload16(W + (size_t)(o0 + row) * CH + k0 + sc * 8, &As[(wave * 32 + c2 * 8) * 64]);
      gload16(X + (size_t)(n0 + row) * CH + k0 + sc * 8, &Bs[(wave * 32 + c2 * 8) * 64]);
    }
    __syncthreads();
#pragma unroll
    for (int s = 0; s < 2; ++s) {
      short8 af[4], bf[4];
#pragma unroll
      for (int i = 0; i < 4; ++i) {
        int m = wm + i * 16 + l16;
        af[i] = *(const short8*)(As + m * 64 + (((s * 4 + quad) ^ (m & 7)) * 8));
        int n = wn + i * 16 + l16;
        bf[i] = *(const short8*)(Bs + n * 64 + (((s * 4 + quad) ^ (n & 7)) * 8));
      }
#pragma unroll
      for (int i = 0; i < 4; ++i)
#pragma unroll
        for (int j = 0; j < 4; ++j)
          acc[i][j] = __builtin_amdgcn_mfma_f32_16x16x32_bf16(af[i], bf[j], acc[i][j], 0, 0, 0);
    }
  }

  if (which < 2) {
    // 0.0625 * log2(e) = 0.090168440
    float qs = (which == 0) ? 0.090168440f : 1.0f;
    unsigned short* outp = (which == 0 ? qT : kT) + (size_t)b * NPIX * CH;
#pragma unroll
    for (int i = 0; i < 4; ++i) {
      int obase = o0 + wm + i * 16 + quad * 4;
      float bias4[4];
#pragma unroll
      for (int r = 0; r < 4; ++r) bias4[r] = bias[obase + r];
#pragma unroll
      for (int j = 0; j < 4; ++j) {
        int n = n0 + wn + j * 16 + l16;
        unsigned long long pk = 0;
#pragma unroll
        for (int r = 0; r < 4; ++r)
          pk |= (unsigned long long)f2bf((acc[i][j][r] + bias4[r]) * qs) << (16 * r);
        *(unsigned long long*)(outp + (size_t)n * CH + obase) = pk;
      }
    }
  } else {
    unsigned short* outp = vC + (size_t)b * CH * NPIX;
#pragma unroll
    for (int i = 0; i < 4; ++i)
#pragma unroll
      for (int r = 0; r < 4; ++r) {
        int o = o0 + wm + i * 16 + quad * 4 + r;
        float bb = bias[o];
#pragma unroll
        for (int j = 0; j < 4; ++j) {
          int n = n0 + wn + j * 16 + l16;
          outp[(size_t)o * NPIX + n] = f2bf(acc[i][j][r] + bb);
        }
      }
  }
}

// ---------------- flash attention (S^T, no-max softmax, 4-way K-split, XCD-pinned b) ----
// grid 2048 x 256 threads (4 waves x 16 q = 64 q/block). KTILE=32, 32 iters.
// b = blockIdx.x & 7 keeps each XCD on one batch's K/V (L2-resident).
// Scores use exp2 with log2e folded into Q; no max subtraction (scores ~N(0,1),
// fp32/bf16 range is ample); O and l accumulate unnormalized, combine divides.
__global__ __launch_bounds__(256, 3) void attn_kernel(
    const unsigned short* __restrict__ qT, const unsigned short* __restrict__ kT,
    const unsigned short* __restrict__ vC, unsigned short* __restrict__ Opart,
    float* __restrict__ ml) {
  __shared__ unsigned short Klds[32 * 256];   // 16KB [k-row][c] chunk-swizzled
  __shared__ unsigned short Vlds[256 * 32];   // 16KB [c][m] chunk-swizzled
  __shared__ unsigned short Plds[4][16 * 32]; // 4KB per-wave P buffers

  const int tid = threadIdx.x;
  const int wave = tid >> 6, lane = tid & 63;
  const int quad = lane >> 4, l16 = lane & 15;
  const int bid = blockIdx.x;
  const int b = bid & 7;
  const int split = (bid >> 3) & 3;
  const int qblk = bid >> 5;            // 0..63
  const int q0 = qblk * 64 + wave * 16;

  const unsigned short* Kb = kT + (size_t)b * NPIX * CH;
  const unsigned short* Vb = vC + (size_t)b * CH * NPIX;

  // Q fragment: B[k=c][n=q], 16 q per wave
  short8 qf[8];
  {
    const unsigned short* qp = qT + ((size_t)(b * NPIX + q0 + l16)) * CH + quad * 8;
#pragma unroll
    for (int s = 0; s < 8; ++s) qf[s] = *(const short8*)(qp + s * 32);
  }

  floatx4 oacc[16];   // O^T: D[c][q]
#pragma unroll
  for (int cb = 0; cb < 16; ++cb) oacc[cb] = (floatx4){0.f, 0.f, 0.f, 0.f};
  float l_i = 0.f;

  unsigned short* Pw = Plds[wave];

  for (int kt = 0; kt < 32; ++kt) {
    const int m0 = split * 1024 + kt * 32;
    __syncthreads();
    if (wave < 2) {
#pragma unroll
      for (int c2 = 0; c2 < 8; ++c2) {
        int krow = wave * 16 + c2 * 2 + (lane >> 5);
        gload16(Kb + (size_t)(m0 + krow) * CH + (((lane & 31) ^ (krow & 7)) * 8),
                &Klds[(wave * 16 + c2 * 2) * CH]);
      }
    } else {
#pragma unroll
      for (int c2 = 0; c2 < 8; ++c2) {
        int vrow = (wave - 2) * 128 + c2 * 16 + (lane >> 2);
        gload16(Vb + (size_t)vrow * NPIX + m0 + (((lane & 3) ^ (vrow & 3)) * 8),
                &Vlds[((wave - 2) * 128 + c2 * 16) * 32]);
      }
    }
    __syncthreads();

    // S^T = K Q^T : D[k][q]
    floatx4 sacc[2];
    sacc[0] = (floatx4){0.f, 0.f, 0.f, 0.f};
    sacc[1] = (floatx4){0.f, 0.f, 0.f, 0.f};
#pragma unroll
    for (int s = 0; s < 8; ++s) {
#pragma unroll
      for (int kb = 0; kb < 2; ++kb) {
        int m = kb * 16 + l16;
        short8 kf = *(const short8*)&Klds[m * CH + (((s * 4 + quad) ^ (m & 7)) * 8)];
        sacc[kb] = __builtin_amdgcn_mfma_f32_16x16x32_bf16(kf, qf[s], sacc[kb], 0, 0, 0);
      }
    }

    // p = 2^s (log2e pre-folded into Q); accumulate l only
    float sum = 0.f;
#pragma unroll
    for (int kb = 0; kb < 2; ++kb)
#pragma unroll
      for (int r = 0; r < 4; ++r) {
        float p = exp2f(sacc[kb][r]);
        sacc[kb][r] = p; sum += p;
      }
    sum += __shfl_xor(sum, 16);
    sum += __shfl_xor(sum, 32);
    l_i += sum;

    // P (rows q=16, cols k=32) -> per-wave LDS, chunk-swizzled
#pragma unroll
    for (int kb = 0; kb < 2; ++kb) {
      int phys = (kb * 2 + (quad >> 1)) ^ (l16 & 3);
      uint2 w;
      w.x = (unsigned int)f2bf(sacc[kb][0]) | ((unsigned int)f2bf(sacc[kb][1]) << 16);
      w.y = (unsigned int)f2bf(sacc[kb][2]) | ((unsigned int)f2bf(sacc[kb][3]) << 16);
      *(uint2*)&Pw[l16 * 32 + phys * 8 + (quad & 1) * 4] = w;
    }
    asm volatile("s_waitcnt lgkmcnt(0)" ::: "memory");
    short8 pf = *(const short8*)&Pw[l16 * 32 + ((quad ^ (l16 & 3)) * 8)];

    // O^T += V P^T
#pragma unroll
    for (int cb = 0; cb < 16; ++cb) {
      int c = cb * 16 + l16;
      short8 vf = *(const short8*)&Vlds[c * 32 + ((quad ^ (c & 3)) * 8)];
      oacc[cb] = __builtin_amdgcn_mfma_f32_16x16x32_bf16(vf, pf, oacc[cb], 0, 0, 0);
    }
  }

  // epilogue: Opart bf16 in lane-linear layout [sb][g][cb][lane*4] (coalesced 512B stores)
  const int sb = split * 8 + b;
  const int g = qblk * 4 + wave;
  unsigned short* op = Opart + (((size_t)sb * 256 + g) * 16) * 256 + lane * 4;
#pragma unroll
  for (int cb = 0; cb < 16; ++cb)
    *(unsigned long long*)(op + cb * 256) = pack4bf(oacc[cb]);
  if (quad == 0) ml[(size_t)sb * NPIX + q0 + l16] = l_i;
}

// ---------------- combine 4 K-split partials -> aT bf16 [n][c] ----------------
// Opart layout matches attn epilogue: elem(sb,g,cb,lane,r), q=g*16+(lane&15),
// c=cb*16+(lane>>4)*4+r
__global__ __launch_bounds__(256) void combine_kernel(const unsigned short* __restrict__ Opart,
                                                      const float* __restrict__ ml,
                                                      unsigned short* __restrict__ aT) {
  int j = blockIdx.x * 256 + threadIdx.x;   // 0..2097151
  int gg = j >> 10;                          // b*256 + g
  int inner = j & 1023;
  int cb = inner >> 6, lane = inner & 63;
  int b = gg >> 8, g = gg & 255;
  int lq = lane & 15, quad = lane >> 4;
  int q = g * 16 + lq;
  float l = 0.f;
  float acc0 = 0.f, acc1 = 0.f, acc2 = 0.f, acc3 = 0.f;
#pragma unroll
  for (int s = 0; s < 4; ++s) {
    int sb = s * 8 + b;
    l += ml[(size_t)sb * NPIX + q];
    uint2 d = *(const uint2*)(Opart + (((size_t)sb * 256 + g) * 16 + cb) * 256 + lane * 4);
    acc0 += bf2f(d.x & 0xffffu); acc1 += bf2f(d.x >> 16);
    acc2 += bf2f(d.y & 0xffffu); acc3 += bf2f(d.y >> 16);
  }
  float inv = 1.f / l;
  floatx4 o; o[0] = acc0 * inv; o[1] = acc1 * inv; o[2] = acc2 * inv; o[3] = acc3 * inv;
  *(unsigned long long*)(aT + ((size_t)(b * NPIX + q)) * CH + cb * 16 + quad * 4) = pack4bf(o);
}

// ---------------- output projection + bias + residual ----------------
__global__ __launch_bounds__(256, 2) void out_gemm(
    const unsigned short* __restrict__ wob, const unsigned short* __restrict__ aT,
    const float* __restrict__ bo, const float* __restrict__ x, float* __restrict__ outp) {
  int nt = blockIdx.x, ot = blockIdx.y, b = blockIdx.z;
  const unsigned short* A = aT + (size_t)b * NPIX * CH;
  int o0 = ot * 128, n0 = nt * 128;

  __shared__ unsigned short As[128 * 64];
  __shared__ unsigned short Bs[128 * 64];

  int tid = threadIdx.x;
  int wave = tid >> 6, lane = tid & 63, quad = lane >> 4, l16 = lane & 15;
  int wm = (wave >> 1) * 64, wn = (wave & 1) * 64;

  floatx4 acc[4][4];
#pragma unroll
  for (int i = 0; i < 4; ++i)
#pragma unroll
    for (int j = 0; j < 4; ++j) acc[i][j] = (floatx4){0.f, 0.f, 0.f, 0.f};

  for (int k0 = 0; k0 < 256; k0 += 64) {
    __syncthreads();
#pragma unroll
    for (int c2 = 0; c2 < 4; ++c2) {
      int row = wave * 32 + c2 * 8 + (lane >> 3);
      int sc = (lane & 7) ^ (row & 7);
      gload16(wob + (size_t)(o0 + row) * CH + k0 + sc * 8, &As[(wave * 32 + c2 * 8) * 64]);
      gload16(A + (size_t)(n0 + row) * CH + k0 + sc * 8, &Bs[(wave * 32 + c2 * 8) * 64]);
    }
    __syncthreads();
#pragma unroll
    for (int s = 0; s < 2; ++s) {
      short8 af[4], bf[4];
#pragma unroll
      for (int i = 0; i < 4; ++i) {
        int m = wm + i * 16 + l16;
        af[i] = *(const short8*)(As + m * 64 + (((s * 4 + quad) ^ (m & 7)) * 8));
        int n = wn + i * 16 + l16;
        bf[i] = *(const short8*)(Bs + n * 64 + (((s * 4 + quad) ^ (n & 7)) * 8));
      }
#pragma unroll
      for (int i = 0; i < 4; ++i)
#pragma unroll
        for (int j = 0; j < 4; ++j)
          acc[i][j] = __builtin_amdgcn_mfma_f32_16x16x32_bf16(af[i], bf[j], acc[i][j], 0, 0, 0);
    }
  }

#pragma unroll
  for (int i = 0; i < 4; ++i)
#pragma unroll
    for (int r = 0; r < 4; ++r) {
      int o = o0 + wm + i * 16 + quad * 4 + r;
      float bb = bo[o];
#pragma unroll
      for (int j = 0; j < 4; ++j) {
        int n = n0 + wn + j * 16 + l16;
        size_t idx = ((size_t)b * CH + o) * NPIX + n;
        outp[idx] = x[idx] + bb + acc[i][j][r];
      }
    }
}

extern "C" void kernel_launch(void* const* d_in, const int* in_sizes, int n_in,
                              void* d_out, int out_size, void* d_ws, size_t ws_size,
                              hipStream_t stream) {
  const float* x   = (const float*)d_in[0];
  const float* gsc = (const float*)d_in[1];
  const float* gbi = (const float*)d_in[2];
  const float* wq  = (const float*)d_in[3];
  const float* bq  = (const float*)d_in[4];
  const float* wk  = (const float*)d_in[5];
  const float* bk  = (const float*)d_in[6];
  const float* wv  = (const float*)d_in[7];
  const float* bv  = (const float*)d_in[8];
  const float* wo  = (const float*)d_in[9];
  const float* bo  = (const float*)d_in[10];
  float* out = (float*)d_out;

  char* ws = (char*)d_ws;
  unsigned short* xnT  = (unsigned short*)(ws);              // 16 MB (dead after qkv)
  float*          ml   = (float*)(ws);                       // 512 KB, reuses xnT region
  unsigned short* qT   = (unsigned short*)(ws + 16777216);   // 16 MB (dead after attn)
  unsigned short* aT   = qT;                                 // reuse
  unsigned short* kT   = (unsigned short*)(ws + 33554432);   // 16 MB
  unsigned short* vC   = (unsigned short*)(ws + 50331648);   // 16 MB
  unsigned short* wqkv = (unsigned short*)(ws + 67108864);   // 384 KB
  unsigned short* wob  = (unsigned short*)(ws + 67502080);   // 128 KB
  unsigned short* Opart= (unsigned short*)(ws + 67633152);   // 64 MB bf16

  conv_weights_kernel<<<256, 256, 0, stream>>>(wq, wk, wv, wo, wqkv, wob);
  gn_kernel<<<256, 256, 0, stream>>>(x, gsc, gbi, xnT);
  dim3 g1(32, 2, 24);
  qkv_gemm<<<g1, 256, 0, stream>>>(wqkv, xnT, bq, bk, bv, qT, kT, vC);
  attn_kernel<<<2048, 256, 0, stream>>>(qT, kT, vC, Opart, ml);
  combine_kernel<<<8192, 256, 0, stream>>>(Opart, ml, aT);
  dim3 g3(32, 2, 8);
  out_gemm<<<g3, 256, 0, stream>>>(wob, aT, bo, x, out);
}

// Round 5
// 358.942 us; speedup vs baseline: 1.2444x; 1.2444x over previous
//
#include <hip/hip_runtime.h>

typedef __attribute__((ext_vector_type(8))) short short8;
typedef __attribute__((ext_vector_type(4))) float floatx4;
typedef __attribute__((ext_vector_type(4))) int intx4;

#define NPIX 4096
#define CH 256

static __device__ __forceinline__ unsigned short f2bf(float f) {
  union { float f; unsigned int u; } v; v.f = f;
  unsigned int u = v.u;
  return (unsigned short)((u + 0x7FFFu + ((u >> 16) & 1u)) >> 16);
}

static __device__ __forceinline__ unsigned long long pack4bf(floatx4 v) {
  return (unsigned long long)f2bf(v[0]) | ((unsigned long long)f2bf(v[1]) << 16) |
         ((unsigned long long)f2bf(v[2]) << 32) | ((unsigned long long)f2bf(v[3]) << 48);
}

typedef __attribute__((address_space(3))) unsigned int lds_uint;
typedef const __attribute__((address_space(1))) unsigned int glob_uint;
static __device__ __forceinline__ void gload16(const void* g, void* l) {
  __builtin_amdgcn_global_load_lds((glob_uint*)g, (lds_uint*)l, 16, 0, 0);
}

// ---------------- weights fp32 -> bf16 ----------------
__global__ void conv_weights_kernel(const float* __restrict__ wq, const float* __restrict__ wk,
                                    const float* __restrict__ wv, const float* __restrict__ wo,
                                    unsigned short* __restrict__ wqkv, unsigned short* __restrict__ wob) {
  int i = blockIdx.x * 256 + threadIdx.x;   // 0..65535
  wqkv[i]          = f2bf(wq[i]);
  wqkv[65536 + i]  = f2bf(wk[i]);
  wqkv[131072 + i] = f2bf(wv[i]);
  wob[i]           = f2bf(wo[i]);
}

// ---------------- GroupNorm -> xnT bf16 [b][n][c] ----------------
__global__ __launch_bounds__(256) void gn_kernel(const float* __restrict__ x,
                                                 const float* __restrict__ gsc,
                                                 const float* __restrict__ gbi,
                                                 unsigned short* __restrict__ xnT) {
  int blk = blockIdx.x; int b = blk >> 5; int g = blk & 31;
  int c0 = g * 8;
  const float* xb = x + ((size_t)b * CH + c0) * NPIX;
  int tid = threadIdx.x;
  float s = 0.f, ss = 0.f;
#pragma unroll
  for (int ci = 0; ci < 8; ++ci) {
    const floatx4* p = (const floatx4*)(xb + (size_t)ci * NPIX);
    for (int n4 = tid; n4 < 1024; n4 += 256) {
      floatx4 v = p[n4];
      s += v[0] + v[1] + v[2] + v[3];
      ss += v[0]*v[0] + v[1]*v[1] + v[2]*v[2] + v[3]*v[3];
    }
  }
#pragma unroll
  for (int o = 32; o > 0; o >>= 1) { s += __shfl_down(s, o); ss += __shfl_down(ss, o); }
  __shared__ float red[10];
  int wid = tid >> 6;
  if ((tid & 63) == 0) { red[wid] = s; red[4 + wid] = ss; }
  __syncthreads();
  if (tid == 0) {
    float S = red[0] + red[1] + red[2] + red[3];
    float SS = red[4] + red[5] + red[6] + red[7];
    float mean = S * (1.f / 32768.f);
    float var = SS * (1.f / 32768.f) - mean * mean;
    red[8] = mean; red[9] = rsqrtf(var + 1e-5f);
  }
  __syncthreads();
  float mean = red[8], rstd = red[9];
  float sc[8], bi[8];
#pragma unroll
  for (int ci = 0; ci < 8; ++ci) {
    float scale = gsc[c0 + ci] * rstd;
    sc[ci] = scale;
    bi[ci] = gbi[c0 + ci] - mean * scale;
  }
  for (int n4 = tid; n4 < 1024; n4 += 256) {
    floatx4 v[8];
#pragma unroll
    for (int ci = 0; ci < 8; ++ci) v[ci] = ((const floatx4*)(xb + (size_t)ci * NPIX))[n4];
#pragma unroll
    for (int j = 0; j < 4; ++j) {
      alignas(16) unsigned short tmp[8];
#pragma unroll
      for (int ci = 0; ci < 8; ++ci) tmp[ci] = f2bf(v[ci][j] * sc[ci] + bi[ci]);
      *(intx4*)(xnT + ((size_t)(b * NPIX + n4 * 4 + j)) * CH + c0) = *(const intx4*)tmp;
    }
  }
}

// ---------------- QKV GEMM: D[o,n] = sum_c W[o,c]*xnT[n,c] + bias ----------------
// q pre-scaled by log2e/16 ; q,k written [n][o] bf16 ; v written [o][n] bf16
__global__ __launch_bounds__(256, 2) void qkv_gemm(
    const unsigned short* __restrict__ wqkv, const unsigned short* __restrict__ xnT,
    const float* __restrict__ bq, const float* __restrict__ bk, const float* __restrict__ bv,
    unsigned short* __restrict__ qT, unsigned short* __restrict__ kT, unsigned short* __restrict__ vC) {
  int nt = blockIdx.x, ot = blockIdx.y, bz = blockIdx.z;
  int which = bz % 3, b = bz / 3;
  const unsigned short* W = wqkv + which * 65536;
  const float* bias = which == 0 ? bq : (which == 1 ? bk : bv);
  const unsigned short* X = xnT + (size_t)b * NPIX * CH;
  int o0 = ot * 128, n0 = nt * 128;

  __shared__ unsigned short As[128 * 64];
  __shared__ unsigned short Bs[128 * 64];

  int tid = threadIdx.x;
  int wave = tid >> 6, lane = tid & 63, quad = lane >> 4, l16 = lane & 15;
  int wm = (wave >> 1) * 64, wn = (wave & 1) * 64;

  floatx4 acc[4][4];
#pragma unroll
  for (int i = 0; i < 4; ++i)
#pragma unroll
    for (int j = 0; j < 4; ++j) acc[i][j] = (floatx4){0.f, 0.f, 0.f, 0.f};

  for (int k0 = 0; k0 < 256; k0 += 64) {
    __syncthreads();
#pragma unroll
    for (int c2 = 0; c2 < 4; ++c2) {
      int row = wave * 32 + c2 * 8 + (lane >> 3);
      int sc = (lane & 7) ^ (row & 7);
      gload16(W + (size_t)(o0 + row) * CH + k0 + sc * 8, &As[(wave * 32 + c2 * 8) * 64]);
      gload16(X + (size_t)(n0 + row) * CH + k0 + sc * 8, &Bs[(wave * 32 + c2 * 8) * 64]);
    }
    __syncthreads();
#pragma unroll
    for (int s = 0; s < 2; ++s) {
      short8 af[4], bf[4];
#pragma unroll
      for (int i = 0; i < 4; ++i) {
        int m = wm + i * 16 + l16;
        af[i] = *(const short8*)(As + m * 64 + (((s * 4 + quad) ^ (m & 7)) * 8));
        int n = wn + i * 16 + l16;
        bf[i] = *(const short8*)(Bs + n * 64 + (((s * 4 + quad) ^ (n & 7)) * 8));
      }
#pragma unroll
      for (int i = 0; i < 4; ++i)
#pragma unroll
        for (int j = 0; j < 4; ++j)
          acc[i][j] = __builtin_amdgcn_mfma_f32_16x16x32_bf16(af[i], bf[j], acc[i][j], 0, 0, 0);
    }
  }

  if (which < 2) {
    // 0.0625 * log2(e)
    float qs = (which == 0) ? 0.090168440f : 1.0f;
    unsigned short* outp = (which == 0 ? qT : kT) + (size_t)b * NPIX * CH;
#pragma unroll
    for (int i = 0; i < 4; ++i) {
      int obase = o0 + wm + i * 16 + quad * 4;
      float bias4[4];
#pragma unroll
      for (int r = 0; r < 4; ++r) bias4[r] = bias[obase + r];
#pragma unroll
      for (int j = 0; j < 4; ++j) {
        int n = n0 + wn + j * 16 + l16;
        unsigned long long pk = 0;
#pragma unroll
        for (int r = 0; r < 4; ++r)
          pk |= (unsigned long long)f2bf((acc[i][j][r] + bias4[r]) * qs) << (16 * r);
        *(unsigned long long*)(outp + (size_t)n * CH + obase) = pk;
      }
    }
  } else {
    unsigned short* outp = vC + (size_t)b * CH * NPIX;
#pragma unroll
    for (int i = 0; i < 4; ++i)
#pragma unroll
      for (int r = 0; r < 4; ++r) {
        int o = o0 + wm + i * 16 + quad * 4 + r;
        float bb = bias[o];
#pragma unroll
        for (int j = 0; j < 4; ++j) {
          int n = n0 + wn + j * 16 + l16;
          outp[(size_t)o * NPIX + n] = f2bf(acc[i][j][r] + bb);
        }
      }
  }
}

// ---------------- fused attention: 1 block per CU, 8 waves, q-tile 128, full m ----------
// grid 256: b = bid&7 (XCD-pinned), qt = bid>>3. KTILE=64, 64 iters, dbuf K/V staging.
// Phase1 (S^T = K·Q^T): wave -> m-slice (w&1)*32, q-slice (w>>1)*32. exp2 (log2e in Q),
// no max-subtraction; P bf16 -> LDS. Phase2 (O^T += V·P^T): wave -> c-slice (w&3)*64,
// q-half (w>>2)*64. l accumulated in-block; normalize + write aT[q][c] in epilogue.
__global__ __launch_bounds__(512) void attn_kernel(
    const unsigned short* __restrict__ qT, const unsigned short* __restrict__ kT,
    const unsigned short* __restrict__ vC, unsigned short* __restrict__ aT) {
  __shared__ unsigned short Klds[2][64 * 256];   // 2 x 32KB, [m][c], XOR-8-chunk swizzle
  __shared__ unsigned short Vlds[2][256 * 64];   // 2 x 32KB, [c][m], XOR-8-chunk swizzle
  __shared__ unsigned short Plds[128 * 64];      // 16KB, [q][m], XOR-8-chunk swizzle
  __shared__ float lred[128][2];

  const int tid = threadIdx.x;
  const int w = tid >> 6, lane = tid & 63;
  const int quad = lane >> 4, l16 = lane & 15;
  const int b = blockIdx.x & 7, qt = blockIdx.x >> 3;
  const int qbase = qt * 128;

  const unsigned short* Kb = kT + (size_t)b * NPIX * CH;
  const unsigned short* Vb = vC + (size_t)b * CH * NPIX;

  const int msl = (w & 1) * 32, qsl = (w >> 1) * 32;   // phase-1 role
  const int csl = (w & 3) * 64, qh = (w >> 2) * 64;    // phase-2 role

  // Q fragments: B[k=c][n=q] for the wave's 2 q-subtiles
  short8 qf[2][8];
#pragma unroll
  for (int qsub = 0; qsub < 2; ++qsub) {
    const unsigned short* qp =
        qT + ((size_t)(b * NPIX + qbase + qsl + qsub * 16 + l16)) * CH + quad * 8;
#pragma unroll
    for (int s = 0; s < 8; ++s) qf[qsub][s] = *(const short8*)(qp + s * 32);
  }

  floatx4 oacc[4][4];   // [csub][qsub] -> D[c][q]
#pragma unroll
  for (int i = 0; i < 4; ++i)
#pragma unroll
    for (int j = 0; j < 4; ++j) oacc[i][j] = (floatx4){0.f, 0.f, 0.f, 0.f};
  float l_acc[2] = {0.f, 0.f};

  // ---- staging: waves 0-3 stage K rows [w*16,w*16+16); waves 4-7 stage V rows ----
#define STAGE(KT)                                                                         \
  {                                                                                       \
    int m0_ = (KT) * 64;                                                                  \
    int bb_ = (KT) & 1;                                                                   \
    if (w < 4) {                                                                          \
      _Pragma("unroll") for (int j = 0; j < 8; ++j) {                                     \
        int r0 = w * 16 + j * 2 + (lane >> 5);                                            \
        gload16(Kb + (size_t)(m0_ + r0) * CH + (((lane & 31) ^ (r0 & 7)) * 8),            \
                &Klds[bb_][(w * 16 + j * 2) * 256]);                                      \
      }                                                                                   \
    } else {                                                                              \
      _Pragma("unroll") for (int j = 0; j < 8; ++j) {                                     \
        int c_ = (w - 4) * 64 + j * 8 + (lane >> 3);                                      \
        gload16(Vb + (size_t)c_ * NPIX + m0_ + (((lane & 7) ^ (c_ & 7)) * 8),             \
                &Vlds[bb_][((w - 4) * 64 + j * 8) * 64]);                                 \
      }                                                                                   \
    }                                                                                     \
  }

  STAGE(0);

  for (int kt = 0; kt < 64; ++kt) {
    const int buf = kt & 1;
    // full barrier: staging for kt (issued one iter ago) must be complete
    asm volatile("s_waitcnt vmcnt(0) lgkmcnt(0)\ns_barrier" ::: "memory");
    if (kt + 1 < 64) STAGE(kt + 1);

    // ---- phase 1: S^T tiles D[m][q] ----
    floatx4 sacc[2][2];
#pragma unroll
    for (int i = 0; i < 2; ++i)
#pragma unroll
      for (int j = 0; j < 2; ++j) sacc[i][j] = (floatx4){0.f, 0.f, 0.f, 0.f};
#pragma unroll
    for (int s = 0; s < 8; ++s) {
#pragma unroll
      for (int msub = 0; msub < 2; ++msub) {
        int m = msl + msub * 16 + l16;
        short8 kf = *(const short8*)&Klds[buf][m * 256 + (((s * 4 + quad) ^ (m & 7)) * 8)];
        sacc[msub][0] = __builtin_amdgcn_mfma_f32_16x16x32_bf16(kf, qf[0][s], sacc[msub][0], 0, 0, 0);
        sacc[msub][1] = __builtin_amdgcn_mfma_f32_16x16x32_bf16(kf, qf[1][s], sacc[msub][1], 0, 0, 0);
      }
    }
    // exp2 + l partial sums
#pragma unroll
    for (int qsub = 0; qsub < 2; ++qsub) {
      float sum = 0.f;
#pragma unroll
      for (int msub = 0; msub < 2; ++msub)
#pragma unroll
        for (int r = 0; r < 4; ++r) {
          float p = exp2f(sacc[msub][qsub][r]);
          sacc[msub][qsub][r] = p; sum += p;
        }
      sum += __shfl_xor(sum, 16);
      sum += __shfl_xor(sum, 32);
      l_acc[qsub] += sum;
    }
    // P -> LDS: element (q = qsl+qsub*16+l16, m = msl+msub*16+quad*4 + r), b64 packed
#pragma unroll
    for (int qsub = 0; qsub < 2; ++qsub) {
      int q = qsl + qsub * 16 + l16;
#pragma unroll
      for (int msub = 0; msub < 2; ++msub) {
        int chunkm = ((msl + msub * 16) >> 3) + (quad >> 1);
        int phys = chunkm ^ (l16 & 7);
        uint2 wv;
        wv.x = (unsigned int)f2bf(sacc[msub][qsub][0]) | ((unsigned int)f2bf(sacc[msub][qsub][1]) << 16);
        wv.y = (unsigned int)f2bf(sacc[msub][qsub][2]) | ((unsigned int)f2bf(sacc[msub][qsub][3]) << 16);
        *(uint2*)&Plds[q * 64 + phys * 8 + (quad & 1) * 4] = wv;
      }
    }
    // LDS-only barrier: P visible; does NOT drain the in-flight prefetch (vmcnt)
    asm volatile("s_waitcnt lgkmcnt(0)\ns_barrier" ::: "memory");

    // ---- phase 2: O^T += V P^T ----
#pragma unroll
    for (int mstep = 0; mstep < 2; ++mstep) {
      short8 pf[4];
#pragma unroll
      for (int qsub = 0; qsub < 4; ++qsub) {
        int q = qh + qsub * 16 + l16;
        pf[qsub] = *(const short8*)&Plds[q * 64 + (((mstep * 4 + quad) ^ (l16 & 7)) * 8)];
      }
#pragma unroll
      for (int csub = 0; csub < 4; ++csub) {
        int c = csl + csub * 16 + l16;
        short8 vf = *(const short8*)&Vlds[buf][c * 64 + (((mstep * 4 + quad) ^ (c & 7)) * 8)];
#pragma unroll
        for (int qsub = 0; qsub < 4; ++qsub)
          oacc[csub][qsub] = __builtin_amdgcn_mfma_f32_16x16x32_bf16(vf, pf[qsub], oacc[csub][qsub], 0, 0, 0);
      }
    }
  }
#undef STAGE

  // ---- l reconciliation across the m-slice wave pairs ----
  if (quad == 0) {
    lred[qsl + l16][w & 1] = l_acc[0];
    lred[qsl + 16 + l16][w & 1] = l_acc[1];
  }
  __syncthreads();
  float inv[4];
#pragma unroll
  for (int qsub = 0; qsub < 4; ++qsub) {
    int q = qh + qsub * 16 + l16;
    inv[qsub] = 1.f / (lred[q][0] + lred[q][1]);
  }
  // ---- store O^T -> aT[q][c] bf16 ----
  unsigned short* ab = aT + (size_t)b * NPIX * CH;
#pragma unroll
  for (int csub = 0; csub < 4; ++csub) {
    int c = csl + csub * 16 + quad * 4;
#pragma unroll
    for (int qsub = 0; qsub < 4; ++qsub) {
      int q = qbase + qh + qsub * 16 + l16;
      floatx4 o = oacc[csub][qsub];
      o[0] *= inv[qsub]; o[1] *= inv[qsub]; o[2] *= inv[qsub]; o[3] *= inv[qsub];
      *(unsigned long long*)(ab + (size_t)q * CH + c) = pack4bf(o);
    }
  }
}

// ---------------- output projection + bias + residual ----------------
__global__ __launch_bounds__(256, 2) void out_gemm(
    const unsigned short* __restrict__ wob, const unsigned short* __restrict__ aT,
    const float* __restrict__ bo, const float* __restrict__ x, float* __restrict__ outp) {
  int nt = blockIdx.x, ot = blockIdx.y, b = blockIdx.z;
  const unsigned short* A = aT + (size_t)b * NPIX * CH;
  int o0 = ot * 128, n0 = nt * 128;

  __shared__ unsigned short As[128 * 64];
  __shared__ unsigned short Bs[128 * 64];

  int tid = threadIdx.x;
  int wave = tid >> 6, lane = tid & 63, quad = lane >> 4, l16 = lane & 15;
  int wm = (wave >> 1) * 64, wn = (wave & 1) * 64;

  floatx4 acc[4][4];
#pragma unroll
  for (int i = 0; i < 4; ++i)
#pragma unroll
    for (int j = 0; j < 4; ++j) acc[i][j] = (floatx4){0.f, 0.f, 0.f, 0.f};

  for (int k0 = 0; k0 < 256; k0 += 64) {
    __syncthreads();
#pragma unroll
    for (int c2 = 0; c2 < 4; ++c2) {
      int row = wave * 32 + c2 * 8 + (lane >> 3);
      int sc = (lane & 7) ^ (row & 7);
      gload16(wob + (size_t)(o0 + row) * CH + k0 + sc * 8, &As[(wave * 32 + c2 * 8) * 64]);
      gload16(A + (size_t)(n0 + row) * CH + k0 + sc * 8, &Bs[(wave * 32 + c2 * 8) * 64]);
    }
    __syncthreads();
#pragma unroll
    for (int s = 0; s < 2; ++s) {
      short8 af[4], bf[4];
#pragma unroll
      for (int i = 0; i < 4; ++i) {
        int m = wm + i * 16 + l16;
        af[i] = *(const short8*)(As + m * 64 + (((s * 4 + quad) ^ (m & 7)) * 8));
        int n = wn + i * 16 + l16;
        bf[i] = *(const short8*)(Bs + n * 64 + (((s * 4 + quad) ^ (n & 7)) * 8));
      }
#pragma unroll
      for (int i = 0; i < 4; ++i)
#pragma unroll
        for (int j = 0; j < 4; ++j)
          acc[i][j] = __builtin_amdgcn_mfma_f32_16x16x32_bf16(af[i], bf[j], acc[i][j], 0, 0, 0);
    }
  }

#pragma unroll
  for (int i = 0; i < 4; ++i)
#pragma unroll
    for (int r = 0; r < 4; ++r) {
      int o = o0 + wm + i * 16 + quad * 4 + r;
      float bb = bo[o];
#pragma unroll
      for (int j = 0; j < 4; ++j) {
        int n = n0 + wn + j * 16 + l16;
        size_t idx = ((size_t)b * CH + o) * NPIX + n;
        outp[idx] = x[idx] + bb + acc[i][j][r];
      }
    }
}

extern "C" void kernel_launch(void* const* d_in, const int* in_sizes, int n_in,
                              void* d_out, int out_size, void* d_ws, size_t ws_size,
                              hipStream_t stream) {
  const float* x   = (const float*)d_in[0];
  const float* gsc = (const float*)d_in[1];
  const float* gbi = (const float*)d_in[2];
  const float* wq  = (const float*)d_in[3];
  const float* bq  = (const float*)d_in[4];
  const float* wk  = (const float*)d_in[5];
  const float* bk  = (const float*)d_in[6];
  const float* wv  = (const float*)d_in[7];
  const float* bv  = (const float*)d_in[8];
  const float* wo  = (const float*)d_in[9];
  const float* bo  = (const float*)d_in[10];
  float* out = (float*)d_out;

  char* ws = (char*)d_ws;
  unsigned short* xnT  = (unsigned short*)(ws);              // 16 MB (dead after qkv)
  unsigned short* qT   = (unsigned short*)(ws + 16777216);   // 16 MB
  unsigned short* kT   = (unsigned short*)(ws + 33554432);   // 16 MB
  unsigned short* vC   = (unsigned short*)(ws + 50331648);   // 16 MB
  unsigned short* wqkv = (unsigned short*)(ws + 67108864);   // 384 KB
  unsigned short* wob  = (unsigned short*)(ws + 67502080);   // 128 KB
  unsigned short* aT   = (unsigned short*)(ws + 67633152);   // 16 MB

  conv_weights_kernel<<<256, 256, 0, stream>>>(wq, wk, wv, wo, wqkv, wob);
  gn_kernel<<<256, 256, 0, stream>>>(x, gsc, gbi, xnT);
  dim3 g1(32, 2, 24);
  qkv_gemm<<<g1, 256, 0, stream>>>(wqkv, xnT, bq, bk, bv, qT, kT, vC);
  attn_kernel<<<256, 512, 0, stream>>>(qT, kT, vC, aT);
  dim3 g3(32, 2, 8);
  out_gemm<<<g3, 256, 0, stream>>>(wob, aT, bo, x, out);
}

// Round 6
// 320.942 us; speedup vs baseline: 1.3918x; 1.1184x over previous
//
#include <hip/hip_runtime.h>

typedef __attribute__((ext_vector_type(8))) short short8;
typedef __attribute__((ext_vector_type(4))) float floatx4;
typedef __attribute__((ext_vector_type(16))) float floatx16;
typedef __attribute__((ext_vector_type(4))) int intx4;

#define NPIX 4096
#define CH 256

static __device__ __forceinline__ unsigned short f2bf(float f) {
  union { float f; unsigned int u; } v; v.f = f;
  unsigned int u = v.u;
  return (unsigned short)((u + 0x7FFFu + ((u >> 16) & 1u)) >> 16);
}

// pack bf16(a) | bf16(b)<<16 : 3 VALU ops (2 int-add round + 1 v_perm)
static __device__ __forceinline__ unsigned int pk2bf(float a, float b) {
  union { float f; unsigned int u; } x, y; x.f = a; y.f = b;
  return __builtin_amdgcn_perm(y.u + 0x8000u, x.u + 0x8000u, 0x07060302u);
}

typedef __attribute__((address_space(3))) unsigned int lds_uint;
typedef const __attribute__((address_space(1))) unsigned int glob_uint;
static __device__ __forceinline__ void gload16(const void* g, void* l) {
  __builtin_amdgcn_global_load_lds((glob_uint*)g, (lds_uint*)l, 16, 0, 0);
}

// ---------------- weights fp32 -> bf16 ----------------
__global__ void conv_weights_kernel(const float* __restrict__ wq, const float* __restrict__ wk,
                                    const float* __restrict__ wv, const float* __restrict__ wo,
                                    unsigned short* __restrict__ wqkv, unsigned short* __restrict__ wob) {
  int i = blockIdx.x * 256 + threadIdx.x;   // 0..65535
  wqkv[i]          = f2bf(wq[i]);
  wqkv[65536 + i]  = f2bf(wk[i]);
  wqkv[131072 + i] = f2bf(wv[i]);
  wob[i]           = f2bf(wo[i]);
}

// ---------------- GroupNorm -> xnT bf16 [b][n][c] ----------------
__global__ __launch_bounds__(256) void gn_kernel(const float* __restrict__ x,
                                                 const float* __restrict__ gsc,
                                                 const float* __restrict__ gbi,
                                                 unsigned short* __restrict__ xnT) {
  int blk = blockIdx.x; int b = blk >> 5; int g = blk & 31;
  int c0 = g * 8;
  const float* xb = x + ((size_t)b * CH + c0) * NPIX;
  int tid = threadIdx.x;
  float s = 0.f, ss = 0.f;
#pragma unroll
  for (int ci = 0; ci < 8; ++ci) {
    const floatx4* p = (const floatx4*)(xb + (size_t)ci * NPIX);
    for (int n4 = tid; n4 < 1024; n4 += 256) {
      floatx4 v = p[n4];
      s += v[0] + v[1] + v[2] + v[3];
      ss += v[0]*v[0] + v[1]*v[1] + v[2]*v[2] + v[3]*v[3];
    }
  }
#pragma unroll
  for (int o = 32; o > 0; o >>= 1) { s += __shfl_down(s, o); ss += __shfl_down(ss, o); }
  __shared__ float red[10];
  int wid = tid >> 6;
  if ((tid & 63) == 0) { red[wid] = s; red[4 + wid] = ss; }
  __syncthreads();
  if (tid == 0) {
    float S = red[0] + red[1] + red[2] + red[3];
    float SS = red[4] + red[5] + red[6] + red[7];
    float mean = S * (1.f / 32768.f);
    float var = SS * (1.f / 32768.f) - mean * mean;
    red[8] = mean; red[9] = rsqrtf(var + 1e-5f);
  }
  __syncthreads();
  float mean = red[8], rstd = red[9];
  float sc[8], bi[8];
#pragma unroll
  for (int ci = 0; ci < 8; ++ci) {
    float scale = gsc[c0 + ci] * rstd;
    sc[ci] = scale;
    bi[ci] = gbi[c0 + ci] - mean * scale;
  }
  for (int n4 = tid; n4 < 1024; n4 += 256) {
    floatx4 v[8];
#pragma unroll
    for (int ci = 0; ci < 8; ++ci) v[ci] = ((const floatx4*)(xb + (size_t)ci * NPIX))[n4];
#pragma unroll
    for (int j = 0; j < 4; ++j) {
      alignas(16) unsigned short tmp[8];
#pragma unroll
      for (int ci = 0; ci < 8; ++ci) tmp[ci] = f2bf(v[ci][j] * sc[ci] + bi[ci]);
      *(intx4*)(xnT + ((size_t)(b * NPIX + n4 * 4 + j)) * CH + c0) = *(const intx4*)tmp;
    }
  }
}

// ---------------- QKV GEMM: D[o,n] = sum_c W[o,c]*xnT[n,c] + bias ----------------
// q pre-scaled by log2e/16 ; q,k written [n][o] bf16 ; v written [o][n] bf16
__global__ __launch_bounds__(256, 2) void qkv_gemm(
    const unsigned short* __restrict__ wqkv, const unsigned short* __restrict__ xnT,
    const float* __restrict__ bq, const float* __restrict__ bk, const float* __restrict__ bv,
    unsigned short* __restrict__ qT, unsigned short* __restrict__ kT, unsigned short* __restrict__ vC) {
  int nt = blockIdx.x, ot = blockIdx.y, bz = blockIdx.z;
  int which = bz % 3, b = bz / 3;
  const unsigned short* W = wqkv + which * 65536;
  const float* bias = which == 0 ? bq : (which == 1 ? bk : bv);
  const unsigned short* X = xnT + (size_t)b * NPIX * CH;
  int o0 = ot * 128, n0 = nt * 128;

  __shared__ unsigned short As[128 * 64];
  __shared__ unsigned short Bs[128 * 64];

  int tid = threadIdx.x;
  int wave = tid >> 6, lane = tid & 63, quad = lane >> 4, l16 = lane & 15;
  int wm = (wave >> 1) * 64, wn = (wave & 1) * 64;

  floatx4 acc[4][4];
#pragma unroll
  for (int i = 0; i < 4; ++i)
#pragma unroll
    for (int j = 0; j < 4; ++j) acc[i][j] = (floatx4){0.f, 0.f, 0.f, 0.f};

  for (int k0 = 0; k0 < 256; k0 += 64) {
    __syncthreads();
#pragma unroll
    for (int c2 = 0; c2 < 4; ++c2) {
      int row = wave * 32 + c2 * 8 + (lane >> 3);
      int sc = (lane & 7) ^ (row & 7);
      gload16(W + (size_t)(o0 + row) * CH + k0 + sc * 8, &As[(wave * 32 + c2 * 8) * 64]);
      gload16(X + (size_t)(n0 + row) * CH + k0 + sc * 8, &Bs[(wave * 32 + c2 * 8) * 64]);
    }
    __syncthreads();
#pragma unroll
    for (int s = 0; s < 2; ++s) {
      short8 af[4], bf[4];
#pragma unroll
      for (int i = 0; i < 4; ++i) {
        int m = wm + i * 16 + l16;
        af[i] = *(const short8*)(As + m * 64 + (((s * 4 + quad) ^ (m & 7)) * 8));
        int n = wn + i * 16 + l16;
        bf[i] = *(const short8*)(Bs + n * 64 + (((s * 4 + quad) ^ (n & 7)) * 8));
      }
#pragma unroll
      for (int i = 0; i < 4; ++i)
#pragma unroll
        for (int j = 0; j < 4; ++j)
          acc[i][j] = __builtin_amdgcn_mfma_f32_16x16x32_bf16(af[i], bf[j], acc[i][j], 0, 0, 0);
    }
  }

  if (which < 2) {
    // 0.0625 * log2(e)
    float qs = (which == 0) ? 0.090168440f : 1.0f;
    unsigned short* outp = (which == 0 ? qT : kT) + (size_t)b * NPIX * CH;
#pragma unroll
    for (int i = 0; i < 4; ++i) {
      int obase = o0 + wm + i * 16 + quad * 4;
      float bias4[4];
#pragma unroll
      for (int r = 0; r < 4; ++r) bias4[r] = bias[obase + r];
#pragma unroll
      for (int j = 0; j < 4; ++j) {
        int n = n0 + wn + j * 16 + l16;
        uint2 pk;
        pk.x = pk2bf((acc[i][j][0] + bias4[0]) * qs, (acc[i][j][1] + bias4[1]) * qs);
        pk.y = pk2bf((acc[i][j][2] + bias4[2]) * qs, (acc[i][j][3] + bias4[3]) * qs);
        *(uint2*)(outp + (size_t)n * CH + obase) = pk;
      }
    }
  } else {
    unsigned short* outp = vC + (size_t)b * CH * NPIX;
#pragma unroll
    for (int i = 0; i < 4; ++i)
#pragma unroll
      for (int r = 0; r < 4; ++r) {
        int o = o0 + wm + i * 16 + quad * 4 + r;
        float bb = bias[o];
#pragma unroll
        for (int j = 0; j < 4; ++j) {
          int n = n0 + wn + j * 16 + l16;
          outp[(size_t)o * NPIX + n] = f2bf(acc[i][j][r] + bb);
        }
      }
  }
}

// ---------------- fused attention: 1 block/CU, 8 waves, q-tile 128, 32x32x16 MFMA ------
// grid 256: b = bid&7 (XCD-pinned), qt = bid>>3. KTILE=64, 64 iters, dbuf K/V staging.
// Phase1 (S^T = K·Q^T, 32x32 tiles): wave -> m-slice (w&1)*32, q-slice (w>>1)*32.
// exp2 (log2e folded into Q), no max-subtraction; P bf16 -> LDS.
// Phase2 (O^T += V·P^T): wave -> c-slice (w&3)*64, q-half (w>>2)*64.
// 32x32x16 layouts: A[m=lane&31][k=(lane>>5)*8+j]; B[k][n=lane&31]; D col=lane&31,
// row=(r&3)+8*(r>>2)+4*(lane>>5).
__global__ __launch_bounds__(512, 2) void attn_kernel(
    const unsigned short* __restrict__ qT, const unsigned short* __restrict__ kT,
    const unsigned short* __restrict__ vC, unsigned short* __restrict__ aT) {
  __shared__ unsigned short Klds[2][64 * 256];   // 2 x 32KB, [m][c], XOR-8-chunk swizzle
  __shared__ unsigned short Vlds[2][256 * 64];   // 2 x 32KB, [c][m], XOR-8-chunk swizzle
  __shared__ unsigned short Plds[128 * 64];      // 16KB, [q][m], XOR-8-chunk swizzle
  __shared__ float lred[128][2];

  const int tid = threadIdx.x;
  const int w = tid >> 6, lane = tid & 63;
  const int l32 = lane & 31, h = lane >> 5;
  const int b = blockIdx.x & 7, qt = blockIdx.x >> 3;
  const int qbase = qt * 128;

  const unsigned short* Kb = kT + (size_t)b * NPIX * CH;
  const unsigned short* Vb = vC + (size_t)b * CH * NPIX;

  const int msl = (w & 1) * 32, qsl = (w >> 1) * 32;   // phase-1 role
  const int csl = (w & 3) * 64, qh = (w >> 2) * 64;    // phase-2 role

  // Q fragments (B-operand): q = qbase+qsl+l32, k=c = s*16 + h*8 + j
  short8 qf[16];
  {
    const unsigned short* qp = qT + ((size_t)(b * NPIX + qbase + qsl + l32)) * CH + h * 8;
#pragma unroll
    for (int s = 0; s < 16; ++s) qf[s] = *(const short8*)(qp + s * 16);
  }

  floatx16 oacc[2][2] = {};   // [csub][qsub] -> D[c][q] 32x32 each
  float l_acc = 0.f;

  // ---- staging: waves 0-3 stage K rows [w*16,w*16+16); waves 4-7 stage V rows ----
#define STAGE(KT)                                                                         \
  {                                                                                       \
    int m0_ = (KT) * 64;                                                                  \
    int bb_ = (KT) & 1;                                                                   \
    if (w < 4) {                                                                          \
      _Pragma("unroll") for (int j = 0; j < 8; ++j) {                                     \
        int r0 = w * 16 + j * 2 + (lane >> 5);                                            \
        gload16(Kb + (size_t)(m0_ + r0) * CH + (((lane & 31) ^ (r0 & 7)) * 8),            \
                &Klds[bb_][(w * 16 + j * 2) * 256]);                                      \
      }                                                                                   \
    } else {                                                                              \
      _Pragma("unroll") for (int j = 0; j < 8; ++j) {                                     \
        int c_ = (w - 4) * 64 + j * 8 + (lane >> 3);                                      \
        gload16(Vb + (size_t)c_ * NPIX + m0_ + (((lane & 7) ^ (c_ & 7)) * 8),             \
                &Vlds[bb_][((w - 4) * 64 + j * 8) * 64]);                                 \
      }                                                                                   \
    }                                                                                     \
  }

  STAGE(0);

  for (int kt = 0; kt < 64; ++kt) {
    const int buf = kt & 1;
    // full barrier: staging for kt (issued one iter ago) must be complete
    asm volatile("s_waitcnt vmcnt(0) lgkmcnt(0)\ns_barrier" ::: "memory");
    if (kt + 1 < 64) STAGE(kt + 1);

    // ---- phase 1: S^T 32x32 tile D[m][q] ----
    floatx16 sacc = {};
    {
      const int m = msl + l32;
      const unsigned short* kr = &Klds[buf][m * 256];
      const int mx = m & 7;
#pragma unroll
      for (int s = 0; s < 16; ++s) {
        short8 kf = *(const short8*)(kr + (((s * 2 + h) ^ mx) * 8));
        sacc = __builtin_amdgcn_mfma_f32_32x32x16_bf16(kf, qf[s], sacc, 0, 0, 0);
      }
    }
    // exp2 + l partial sum (all 16 regs share q = l32; halves differ in m)
    float sum = 0.f;
#pragma unroll
    for (int r = 0; r < 16; ++r) {
      float p = exp2f(sacc[r]);
      sacc[r] = p; sum += p;
    }
    sum += __shfl_xor(sum, 32);
    l_acc += sum;

    // P -> LDS: lane holds (q = qsl+l32, m = msl + 8*t + 4*h + i) for reg r = 4t+i
    {
      int qrow = qsl + l32;
#pragma unroll
      for (int t = 0; t < 4; ++t) {
        int phys = ((msl >> 3) + t) ^ (qrow & 7);
        uint2 wv;
        wv.x = pk2bf(sacc[4 * t], sacc[4 * t + 1]);
        wv.y = pk2bf(sacc[4 * t + 2], sacc[4 * t + 3]);
        *(uint2*)&Plds[qrow * 64 + phys * 8 + h * 4] = wv;
      }
    }
    // LDS-only barrier: P visible; does NOT drain the in-flight prefetch (vmcnt)
    asm volatile("s_waitcnt lgkmcnt(0)\ns_barrier" ::: "memory");

    // ---- phase 2: O^T += V P^T (32x32 tiles) ----
#pragma unroll
    for (int mstep = 0; mstep < 4; ++mstep) {
      short8 pf[2], vf[2];
#pragma unroll
      for (int qsub = 0; qsub < 2; ++qsub) {
        int q = qh + qsub * 32 + l32;
        pf[qsub] = *(const short8*)&Plds[q * 64 + (((mstep * 2 + h) ^ (q & 7)) * 8)];
      }
#pragma unroll
      for (int csub = 0; csub < 2; ++csub) {
        int c = csl + csub * 32 + l32;
        vf[csub] = *(const short8*)&Vlds[buf][c * 64 + (((mstep * 2 + h) ^ (c & 7)) * 8)];
      }
#pragma unroll
      for (int csub = 0; csub < 2; ++csub)
#pragma unroll
        for (int qsub = 0; qsub < 2; ++qsub)
          oacc[csub][qsub] =
              __builtin_amdgcn_mfma_f32_32x32x16_bf16(vf[csub], pf[qsub], oacc[csub][qsub], 0, 0, 0);
    }
  }
#undef STAGE

  // ---- l reconciliation across the two m-slice waves per q-slice ----
  if (lane < 32) lred[qsl + l32][w & 1] = l_acc;
  __syncthreads();
  float inv[2];
#pragma unroll
  for (int qsub = 0; qsub < 2; ++qsub) {
    int q = qh + qsub * 32 + l32;
    inv[qsub] = 1.f / (lred[q][0] + lred[q][1]);
  }
  // ---- store O^T -> aT[q][c] bf16 ----
  unsigned short* ab = aT + (size_t)b * NPIX * CH;
#pragma unroll
  for (int csub = 0; csub < 2; ++csub)
#pragma unroll
    for (int qsub = 0; qsub < 2; ++qsub) {
      int qg = qbase + qh + qsub * 32 + l32;
      float iv = inv[qsub];
#pragma unroll
      for (int t = 0; t < 4; ++t) {
        int c = csl + csub * 32 + 8 * t + 4 * h;
        uint2 wv;
        wv.x = pk2bf(oacc[csub][qsub][4 * t] * iv, oacc[csub][qsub][4 * t + 1] * iv);
        wv.y = pk2bf(oacc[csub][qsub][4 * t + 2] * iv, oacc[csub][qsub][4 * t + 3] * iv);
        *(uint2*)(ab + (size_t)qg * CH + c) = wv;
      }
    }
}

// ---------------- output projection + bias + residual ----------------
__global__ __launch_bounds__(256, 2) void out_gemm(
    const unsigned short* __restrict__ wob, const unsigned short* __restrict__ aT,
    const float* __restrict__ bo, const float* __restrict__ x, float* __restrict__ outp) {
  int nt = blockIdx.x, ot = blockIdx.y, b = blockIdx.z;
  const unsigned short* A = aT + (size_t)b * NPIX * CH;
  int o0 = ot * 128, n0 = nt * 128;

  __shared__ unsigned short As[128 * 64];
  __shared__ unsigned short Bs[128 * 64];

  int tid = threadIdx.x;
  int wave = tid >> 6, lane = tid & 63, quad = lane >> 4, l16 = lane & 15;
  int wm = (wave >> 1) * 64, wn = (wave & 1) * 64;

  floatx4 acc[4][4];
#pragma unroll
  for (int i = 0; i < 4; ++i)
#pragma unroll
    for (int j = 0; j < 4; ++j) acc[i][j] = (floatx4){0.f, 0.f, 0.f, 0.f};

  for (int k0 = 0; k0 < 256; k0 += 64) {
    __syncthreads();
#pragma unroll
    for (int c2 = 0; c2 < 4; ++c2) {
      int row = wave * 32 + c2 * 8 + (lane >> 3);
      int sc = (lane & 7) ^ (row & 7);
      gload16(wob + (size_t)(o0 + row) * CH + k0 + sc * 8, &As[(wave * 32 + c2 * 8) * 64]);
      gload16(A + (size_t)(n0 + row) * CH + k0 + sc * 8, &Bs[(wave * 32 + c2 * 8) * 64]);
    }
    __syncthreads();
#pragma unroll
    for (int s = 0; s < 2; ++s) {
      short8 af[4], bf[4];
#pragma unroll
      for (int i = 0; i < 4; ++i) {
        int m = wm + i * 16 + l16;
        af[i] = *(const short8*)(As + m * 64 + (((s * 4 + quad) ^ (m & 7)) * 8));
        int n = wn + i * 16 + l16;
        bf[i] = *(const short8*)(Bs + n * 64 + (((s * 4 + quad) ^ (n & 7)) * 8));
      }
#pragma unroll
      for (int i = 0; i < 4; ++i)
#pragma unroll
        for (int j = 0; j < 4; ++j)
          acc[i][j] = __builtin_amdgcn_mfma_f32_16x16x32_bf16(af[i], bf[j], acc[i][j], 0, 0, 0);
    }
  }

#pragma unroll
  for (int i = 0; i < 4; ++i)
#pragma unroll
    for (int r = 0; r < 4; ++r) {
      int o = o0 + wm + i * 16 + quad * 4 + r;
      float bb = bo[o];
#pragma unroll
      for (int j = 0; j < 4; ++j) {
        int n = n0 + wn + j * 16 + l16;
        size_t idx = ((size_t)b * CH + o) * NPIX + n;
        outp[idx] = x[idx] + bb + acc[i][j][r];
      }
    }
}

extern "C" void kernel_launch(void* const* d_in, const int* in_sizes, int n_in,
                              void* d_out, int out_size, void* d_ws, size_t ws_size,
                              hipStream_t stream) {
  const float* x   = (const float*)d_in[0];
  const float* gsc = (const float*)d_in[1];
  const float* gbi = (const float*)d_in[2];
  const float* wq  = (const float*)d_in[3];
  const float* bq  = (const float*)d_in[4];
  const float* wk  = (const float*)d_in[5];
  const float* bk  = (const float*)d_in[6];
  const float* wv  = (const float*)d_in[7];
  const float* bv  = (const float*)d_in[8];
  const float* wo  = (const float*)d_in[9];
  const float* bo  = (const float*)d_in[10];
  float* out = (float*)d_out;

  char* ws = (char*)d_ws;
  unsigned short* xnT  = (unsigned short*)(ws);              // 16 MB (dead after qkv)
  unsigned short* qT   = (unsigned short*)(ws + 16777216);   // 16 MB
  unsigned short* kT   = (unsigned short*)(ws + 33554432);   // 16 MB
  unsigned short* vC   = (unsigned short*)(ws + 50331648);   // 16 MB
  unsigned short* wqkv = (unsigned short*)(ws + 67108864);   // 384 KB
  unsigned short* wob  = (unsigned short*)(ws + 67502080);   // 128 KB
  unsigned short* aT   = (unsigned short*)(ws + 67633152);   // 16 MB

  conv_weights_kernel<<<256, 256, 0, stream>>>(wq, wk, wv, wo, wqkv, wob);
  gn_kernel<<<256, 256, 0, stream>>>(x, gsc, gbi, xnT);
  dim3 g1(32, 2, 24);
  qkv_gemm<<<g1, 256, 0, stream>>>(wqkv, xnT, bq, bk, bv, qT, kT, vC);
  attn_kernel<<<256, 512, 0, stream>>>(qT, kT, vC, aT);
  dim3 g3(32, 2, 8);
  out_gemm<<<g3, 256, 0, stream>>>(wob, aT, bo, x, out);
}